// Round 8
// baseline (189.630 us; speedup 1.0000x reference)
//
#include <hip/hip_runtime.h>
#include <stdint.h>

typedef __bf16 bf16x8 __attribute__((ext_vector_type(8)));
typedef float  f32x4  __attribute__((ext_vector_type(4)));
typedef float  f32x16 __attribute__((ext_vector_type(16)));
typedef unsigned short u16;
typedef unsigned int   u32;

#define B_  2
#define S_  2048
#define H_  1024
#define NH_ 16
#define HD_ 64
#define QSCL 0.18033688011112042f  /* 0.125 * log2(e) */

__device__ __forceinline__ u16 f2bf(float f) {
  u32 u = __builtin_bit_cast(u32, f);
  return (u16)((u + 0x7FFFu + ((u >> 16) & 1u)) >> 16);
}
__device__ __forceinline__ float ex2(float x) { return __builtin_amdgcn_exp2f(x); }
__device__ __forceinline__ u32 cvtpk(float lo, float hi) {
  u32 r; asm("v_cvt_pk_bf16_f32 %0, %1, %2" : "=v"(r) : "v"(lo), "v"(hi)); return r;
}
__device__ __forceinline__ void gload_lds16(const u16* g, u16* lds) {
  __builtin_amdgcn_global_load_lds(
      (__attribute__((address_space(1))) void*)(void*)g,
      (__attribute__((address_space(3))) void*)lds, 16, 0, 0);
}

__global__ void cvt_all(const float* __restrict__ a, const float* __restrict__ b,
                        const float* __restrict__ c, u16* __restrict__ oa,
                        u16* __restrict__ ob, u16* __restrict__ oc) {
  int i = blockIdx.x * 256 + threadIdx.x;
  const float4* src; ushort4* dst; int j;
  if (i < 1048576)      { src = (const float4*)a; dst = (ushort4*)oa; j = i; }
  else if (i < 1835008) { src = (const float4*)b; dst = (ushort4*)ob; j = i - 1048576; }
  else                  { src = (const float4*)c; dst = (ushort4*)oc; j = i - 1835008; }
  const float4 v = src[j];
  ushort4 o;
  o.x = f2bf(v.x); o.y = f2bf(v.y); o.z = f2bf(v.z); o.w = f2bf(v.w);
  dst[j] = o;
}

// QKV GEMM: C = A[M,K] * W[N,K]^T + bias, scatter bf16 to q (pre-scaled)/k/vt.
// 2-phase double-buffered staging: stage k+1 while computing k, 1 barrier/iter.
__global__ __launch_bounds__(256, 2)
void gemm_qkv(const u16* __restrict__ A, const u16* __restrict__ W,
              const float* __restrict__ bias,
              u16* __restrict__ qb, u16* __restrict__ kb, u16* __restrict__ vtb,
              int M, int N, int K)
{
  __shared__ __align__(16) u16 As[2][128 * 32];
  __shared__ __align__(16) u16 Bs[2][128 * 32];
  const int tid = threadIdx.x;
  const int w = tid >> 6, l = tid & 63;
  const int lg = l >> 4, lr = l & 15;
  const int wr = w >> 1, wc = w & 1;
  const int tM = blockIdx.y * 128, tN = blockIdx.x * 128;

  f32x4 acc[4][4];
  const f32x4 z4 = {0.f, 0.f, 0.f, 0.f};
#pragma unroll
  for (int m = 0; m < 4; ++m)
#pragma unroll
    for (int n = 0; n < 4; ++n) acc[m][n] = z4;

  auto STG = [&](int buf, int k0) {
#pragma unroll
    for (int i = 0; i < 2; ++i) {
      const int ch = i * 256 + tid;
      const int row = ch >> 2, cc = (ch & 3) * 8;
      gload_lds16(A + (size_t)(tM + row) * K + k0 + cc, As[buf] + (size_t)(i * 256 + w * 64) * 8);
      gload_lds16(W + (size_t)(tN + row) * K + k0 + cc, Bs[buf] + (size_t)(i * 256 + w * 64) * 8);
    }
  };

  STG(0, 0);
  __syncthreads();

  for (int it = 0; it < K / 32; ++it) {
    const int cur = it & 1;
    if (it + 1 < K / 32) STG(cur ^ 1, (it + 1) * 32);
    bf16x8 af[4], bw[4];
#pragma unroll
    for (int m = 0; m < 4; ++m)
      af[m] = *(const bf16x8*)&As[cur][(wr * 64 + m * 16 + lr) * 32 + lg * 8];
#pragma unroll
    for (int n = 0; n < 4; ++n)
      bw[n] = *(const bf16x8*)&Bs[cur][(wc * 64 + n * 16 + lr) * 32 + lg * 8];
#pragma unroll
    for (int m = 0; m < 4; ++m)
#pragma unroll
      for (int n = 0; n < 4; ++n)
        acc[m][n] = __builtin_amdgcn_mfma_f32_16x16x32_bf16(af[m], bw[n], acc[m][n], 0, 0, 0);
    __syncthreads();
  }

#pragma unroll
  for (int n = 0; n < 4; ++n) {
    const int col = tN + wc * 64 + n * 16 + lr;
    const float bv = bias[col];
    const int t3 = col >> 10, rem = col & 1023;
    const int hh = rem >> 6, dd = rem & 63;
    const float sc = (t3 == 0) ? QSCL : 1.f;
    u16* dst = (t3 == 0) ? qb : (t3 == 1) ? kb : vtb;
#pragma unroll
    for (int m = 0; m < 4; ++m)
#pragma unroll
      for (int r = 0; r < 4; ++r) {
        const int row = tM + wr * 64 + m * 16 + lg * 4 + r;
        const int bb = row >> 11, ss = row & 2047;
        const u16 val = f2bf((acc[m][n][r] + bv) * sc);
        if (t3 < 2) dst[((size_t)(bb * NH_ + hh) * S_ + ss) * HD_ + dd] = val;
        else        dst[((size_t)(bb * NH_ + hh) * HD_ + dd) * S_ + ss] = val;
      }
  }
}

// Out-proj: C = A[M,K] * W[N,K]^T + bias, fp32 out. 128x64 tiles, 2-phase dbuf.
__global__ __launch_bounds__(256, 2)
void gemm_out(const u16* __restrict__ A, const u16* __restrict__ W,
              const float* __restrict__ bias, float* __restrict__ outf,
              int M, int N, int K)
{
  __shared__ __align__(16) u16 As[2][128 * 32];
  __shared__ __align__(16) u16 Bs[2][64 * 32];
  const int tid = threadIdx.x;
  const int w = tid >> 6, l = tid & 63;
  const int lg = l >> 4, lr = l & 15;
  const int tM = blockIdx.y * 128, tN = blockIdx.x * 64;

  f32x4 acc[2][4];
  const f32x4 z4 = {0.f, 0.f, 0.f, 0.f};
#pragma unroll
  for (int m = 0; m < 2; ++m)
#pragma unroll
    for (int n = 0; n < 4; ++n) acc[m][n] = z4;

  auto STG = [&](int buf, int k0) {
#pragma unroll
    for (int i = 0; i < 2; ++i) {
      const int ch = i * 256 + tid;
      const int row = ch >> 2, cc = (ch & 3) * 8;
      gload_lds16(A + (size_t)(tM + row) * K + k0 + cc, As[buf] + (size_t)(i * 256 + w * 64) * 8);
    }
    gload_lds16(W + (size_t)(tN + (tid >> 2)) * K + k0 + (tid & 3) * 8, Bs[buf] + (size_t)(w * 64) * 8);
  };

  STG(0, 0);
  __syncthreads();

  for (int it = 0; it < K / 32; ++it) {
    const int cur = it & 1;
    if (it + 1 < K / 32) STG(cur ^ 1, (it + 1) * 32);
    bf16x8 af[2], bw[4];
#pragma unroll
    for (int m = 0; m < 2; ++m)
      af[m] = *(const bf16x8*)&As[cur][(w * 32 + m * 16 + lr) * 32 + lg * 8];
#pragma unroll
    for (int n = 0; n < 4; ++n)
      bw[n] = *(const bf16x8*)&Bs[cur][(n * 16 + lr) * 32 + lg * 8];
#pragma unroll
    for (int m = 0; m < 2; ++m)
#pragma unroll
      for (int n = 0; n < 4; ++n)
        acc[m][n] = __builtin_amdgcn_mfma_f32_16x16x32_bf16(af[m], bw[n], acc[m][n], 0, 0, 0);
    __syncthreads();
  }

#pragma unroll
  for (int n = 0; n < 4; ++n) {
    const int col = tN + n * 16 + lr;
    const float bv = bias[col];
#pragma unroll
    for (int m = 0; m < 2; ++m)
#pragma unroll
      for (int r = 0; r < 4; ++r) {
        const int row = tM + w * 32 + m * 16 + lg * 4 + r;
        outf[(size_t)row * N + col] = acc[m][n][r] + bv;
      }
  }
}

// Flash attention, LDS-FREE: MFMA fragments loaded directly from global
// (L1/L2-resident: per-XCD K/V working set = 4 bh x 512 KB = 2 MB < 4 MB L2,
// bh in low 5 grid bits -> same-XCD locality, R4-verified via FETCH_SIZE).
// No barriers in the loop, no bank conflicts, free-running waves.
// 32x32x16 MFMA, in-register P (cvt_pk + permlane32_swap), zero-shift softmax.
// K prefetched one iter ahead (kA/kB sets); V issued early under QK^T+softmax.
__global__ __launch_bounds__(256, 2)
void attn_fwd(const u16* __restrict__ qb, const u16* __restrict__ kb,
              const u16* __restrict__ vtb, u16* __restrict__ ob)
{
  const int tid = threadIdx.x;
  const int w = tid >> 6, l = tid & 63;
  const int q32 = l & 31, hi = l >> 5;
  const int idx = blockIdx.x;
  const int bh = idx & 31, qt = idx >> 5;
  const int bb = bh >> 4, hh = bh & 15;
  const int q0 = qt * 128 + w * 32;

  // Q (B-operand): lane holds Q[q0+q32][ks*16 + hi*8 + j]
  bf16x8 qf[4];
#pragma unroll
  for (int ks = 0; ks < 4; ++ks)
    qf[ks] = *(const bf16x8*)&qb[((size_t)bh * S_ + q0 + q32) * HD_ + ks * 16 + hi * 8];

  // per-lane fragment base pointers
  const u16* kfb = kb  + ((size_t)bh * S_  + q32) * HD_ + hi * 8;  // + (kv0+kt*32)*HD_ + ks*16
  const u16* vfb = vtb + ((size_t)bh * HD_ + q32) * S_  + hi * 8;  // + dt*32*S_ + kv0 + kv*16

  const f32x16 z16 = {};
  f32x16 acc[2] = {z16, z16};
  float lrun = 0.f;

  bf16x8 kA[2][4], kB[2][4];

#define LOADK(DST, T)                                                         \
  { _Pragma("unroll") for (int kt = 0; kt < 2; ++kt)                          \
    _Pragma("unroll") for (int ks = 0; ks < 4; ++ks)                          \
      DST[kt][ks] = *(const bf16x8*)(kfb + (size_t)((T) * 64 + kt * 32) * HD_ + ks * 16); }

#define ABODY(KC, KN, TCUR, TNXT)                                             \
  {                                                                           \
    bf16x8 vf[2][4];                                                          \
    _Pragma("unroll") for (int dt = 0; dt < 2; ++dt)                          \
    _Pragma("unroll") for (int kv = 0; kv < 4; ++kv)                          \
      vf[dt][kv] = *(const bf16x8*)(vfb + (size_t)dt * 32 * S_ + (TCUR) * 64 + kv * 16); \
    LOADK(KN, TNXT);                                                          \
    f32x16 st0 = z16, st1 = z16;                                              \
    __builtin_amdgcn_s_setprio(1);                                            \
    _Pragma("unroll") for (int ks = 0; ks < 4; ++ks) {                        \
      st0 = __builtin_amdgcn_mfma_f32_32x32x16_bf16(KC[0][ks], qf[ks], st0, 0, 0, 0); \
      st1 = __builtin_amdgcn_mfma_f32_32x32x16_bf16(KC[1][ks], qf[ks], st1, 0, 0, 0); \
    }                                                                         \
    __builtin_amdgcn_s_setprio(0);                                            \
    bf16x8 pa[4];                                                             \
    _Pragma("unroll") for (int kt = 0; kt < 2; ++kt) {                        \
      const f32x16 stt = kt ? st1 : st0;                                      \
      float p[16];                                                            \
      _Pragma("unroll") for (int r = 0; r < 16; ++r) p[r] = ex2(stt[r]);      \
      _Pragma("unroll") for (int g = 0; g < 4; ++g)                           \
        lrun += (p[4 * g] + p[4 * g + 1]) + (p[4 * g + 2] + p[4 * g + 3]);    \
      u32 wk0[4], wk1[4];                                                     \
      _Pragma("unroll") for (int g = 0; g < 4; ++g) {                         \
        wk0[g] = cvtpk(p[4 * g], p[4 * g + 1]);                               \
        wk1[g] = cvtpk(p[4 * g + 2], p[4 * g + 3]);                           \
      }                                                                       \
      _Pragma("unroll") for (int k2 = 0; k2 < 2; ++k2) {                      \
        u32 a0 = wk0[2 * k2], b0 = wk0[2 * k2 + 1];                           \
        u32 a1 = wk1[2 * k2], b1 = wk1[2 * k2 + 1];                           \
        asm volatile("v_permlane32_swap_b32 %0, %1" : "+v"(a0), "+v"(b0));    \
        asm volatile("v_permlane32_swap_b32 %0, %1" : "+v"(a1), "+v"(b1));    \
        uint4 wv = {a0, a1, b0, b1};                                          \
        pa[kt * 2 + k2] = __builtin_bit_cast(bf16x8, wv);                     \
      }                                                                       \
    }                                                                         \
    __builtin_amdgcn_s_setprio(1);                                            \
    _Pragma("unroll") for (int dt = 0; dt < 2; ++dt)                          \
    _Pragma("unroll") for (int kv = 0; kv < 4; ++kv)                          \
      acc[dt] = __builtin_amdgcn_mfma_f32_32x32x16_bf16(vf[dt][kv], pa[kv], acc[dt], 0, 0, 0); \
    __builtin_amdgcn_s_setprio(0);                                            \
  }

  LOADK(kA, 0);
  for (int t = 0; t < 32; t += 2) {
    ABODY(kA, kB, t, t + 1);
    ABODY(kB, kA, t + 1, (t + 2 < 32) ? t + 2 : 0);
  }
#undef ABODY
#undef LOADK

  lrun += __shfl_xor(lrun, 32);
  const float linv = 1.f / lrun;
  const size_t orow = ((size_t)(bb * S_ + q0 + q32)) * H_ + hh * HD_;
#pragma unroll
  for (int dt = 0; dt < 2; ++dt)
#pragma unroll
    for (int g = 0; g < 4; ++g) {
      const u32 o0 = cvtpk(acc[dt][4 * g] * linv, acc[dt][4 * g + 1] * linv);
      const u32 o1 = cvtpk(acc[dt][4 * g + 2] * linv, acc[dt][4 * g + 3] * linv);
      uint2 ov; ov.x = o0; ov.y = o1;
      *(uint2*)&ob[orow + dt * 32 + g * 8 + hi * 4] = ov;
    }
}

extern "C" void kernel_launch(void* const* d_in, const int* in_sizes, int n_in,
                              void* d_out, int out_size, void* d_ws, size_t ws_size,
                              hipStream_t stream) {
  const float* x     = (const float*)d_in[0];
  const float* qkv_w = (const float*)d_in[1];
  const float* qkv_b = (const float*)d_in[2];
  const float* out_w = (const float*)d_in[3];
  const float* out_b = (const float*)d_in[4];

  char* ws = (char*)d_ws;
  u16* xb    = (u16*)(ws);
  u16* wqkvb = (u16*)(ws + 8388608);
  u16* wob   = (u16*)(ws + 14680064);
  u16* qb    = (u16*)(ws + 16777216);
  u16* kb    = (u16*)(ws + 25165824);
  u16* vtb   = (u16*)(ws + 33554432);   // V transposed: [b,h,d,s]
  u16* ob    = (u16*)(ws + 41943040);

  cvt_all<<<8192, 256, 0, stream>>>(x, qkv_w, out_w, xb, wqkvb, wob);

  gemm_qkv<<<dim3(24, 32), 256, 0, stream>>>(xb, wqkvb, qkv_b,
                                             qb, kb, vtb, 4096, 3072, 1024);
  attn_fwd<<<512, 256, 0, stream>>>(qb, kb, vtb, ob);
  gemm_out<<<dim3(16, 32), 256, 0, stream>>>(ob, wob, out_b, (float*)d_out,
                                             4096, 1024, 1024);
}

// Round 9
// 122.435 us; speedup vs baseline: 1.5488x; 1.5488x over previous
//
#include <hip/hip_runtime.h>
#include <stdint.h>

typedef __bf16 bf16x8 __attribute__((ext_vector_type(8)));
typedef float  f32x4  __attribute__((ext_vector_type(4)));
typedef float  f32x16 __attribute__((ext_vector_type(16)));
typedef unsigned short u16;
typedef unsigned int   u32;

#define B_  2
#define S_  2048
#define H_  1024
#define NH_ 16
#define HD_ 64
#define QSCL 0.18033688011112042f  /* 0.125 * log2(e) */

__device__ __forceinline__ u16 f2bf(float f) {
  u32 u = __builtin_bit_cast(u32, f);
  return (u16)((u + 0x7FFFu + ((u >> 16) & 1u)) >> 16);
}
__device__ __forceinline__ float ex2(float x) { return __builtin_amdgcn_exp2f(x); }
__device__ __forceinline__ u32 cvtpk(float lo, float hi) {
  u32 r; asm("v_cvt_pk_bf16_f32 %0, %1, %2" : "=v"(r) : "v"(lo), "v"(hi)); return r;
}
__device__ __forceinline__ void gload_lds16(const u16* g, u16* lds) {
  __builtin_amdgcn_global_load_lds(
      (__attribute__((address_space(1))) void*)(void*)g,
      (__attribute__((address_space(3))) void*)lds, 16, 0, 0);
}

__global__ void cvt_all(const float* __restrict__ a, const float* __restrict__ b,
                        const float* __restrict__ c, u16* __restrict__ oa,
                        u16* __restrict__ ob, u16* __restrict__ oc) {
  int i = blockIdx.x * 256 + threadIdx.x;
  const float4* src; ushort4* dst; int j;
  if (i < 1048576)      { src = (const float4*)a; dst = (ushort4*)oa; j = i; }
  else if (i < 1835008) { src = (const float4*)b; dst = (ushort4*)ob; j = i - 1048576; }
  else                  { src = (const float4*)c; dst = (ushort4*)oc; j = i - 1835008; }
  const float4 v = src[j];
  ushort4 o;
  o.x = f2bf(v.x); o.y = f2bf(v.y); o.z = f2bf(v.z); o.w = f2bf(v.w);
  dst[j] = o;
}

// QKV GEMM: C = A[M,K] * W[N,K]^T + bias, scatter bf16 to q (pre-scaled)/k/vt.
// 2-phase double-buffered staging (R8 form, kept).
__global__ __launch_bounds__(256, 2)
void gemm_qkv(const u16* __restrict__ A, const u16* __restrict__ W,
              const float* __restrict__ bias,
              u16* __restrict__ qb, u16* __restrict__ kb, u16* __restrict__ vtb,
              int M, int N, int K)
{
  __shared__ __align__(16) u16 As[2][128 * 32];
  __shared__ __align__(16) u16 Bs[2][128 * 32];
  const int tid = threadIdx.x;
  const int w = tid >> 6, l = tid & 63;
  const int lg = l >> 4, lr = l & 15;
  const int wr = w >> 1, wc = w & 1;
  const int tM = blockIdx.y * 128, tN = blockIdx.x * 128;

  f32x4 acc[4][4];
  const f32x4 z4 = {0.f, 0.f, 0.f, 0.f};
#pragma unroll
  for (int m = 0; m < 4; ++m)
#pragma unroll
    for (int n = 0; n < 4; ++n) acc[m][n] = z4;

  auto STG = [&](int buf, int k0) {
#pragma unroll
    for (int i = 0; i < 2; ++i) {
      const int ch = i * 256 + tid;
      const int row = ch >> 2, cc = (ch & 3) * 8;
      gload_lds16(A + (size_t)(tM + row) * K + k0 + cc, As[buf] + (size_t)(i * 256 + w * 64) * 8);
      gload_lds16(W + (size_t)(tN + row) * K + k0 + cc, Bs[buf] + (size_t)(i * 256 + w * 64) * 8);
    }
  };

  STG(0, 0);
  __syncthreads();

  for (int it = 0; it < K / 32; ++it) {
    const int cur = it & 1;
    if (it + 1 < K / 32) STG(cur ^ 1, (it + 1) * 32);
    bf16x8 af[4], bw[4];
#pragma unroll
    for (int m = 0; m < 4; ++m)
      af[m] = *(const bf16x8*)&As[cur][(wr * 64 + m * 16 + lr) * 32 + lg * 8];
#pragma unroll
    for (int n = 0; n < 4; ++n)
      bw[n] = *(const bf16x8*)&Bs[cur][(wc * 64 + n * 16 + lr) * 32 + lg * 8];
#pragma unroll
    for (int m = 0; m < 4; ++m)
#pragma unroll
      for (int n = 0; n < 4; ++n)
        acc[m][n] = __builtin_amdgcn_mfma_f32_16x16x32_bf16(af[m], bw[n], acc[m][n], 0, 0, 0);
    __syncthreads();
  }

#pragma unroll
  for (int n = 0; n < 4; ++n) {
    const int col = tN + wc * 64 + n * 16 + lr;
    const float bv = bias[col];
    const int t3 = col >> 10, rem = col & 1023;
    const int hh = rem >> 6, dd = rem & 63;
    const float sc = (t3 == 0) ? QSCL : 1.f;
    u16* dst = (t3 == 0) ? qb : (t3 == 1) ? kb : vtb;
#pragma unroll
    for (int m = 0; m < 4; ++m)
#pragma unroll
      for (int r = 0; r < 4; ++r) {
        const int row = tM + wr * 64 + m * 16 + lg * 4 + r;
        const int bb = row >> 11, ss = row & 2047;
        const u16 val = f2bf((acc[m][n][r] + bv) * sc);
        if (t3 < 2) dst[((size_t)(bb * NH_ + hh) * S_ + ss) * HD_ + dd] = val;
        else        dst[((size_t)(bb * NH_ + hh) * HD_ + dd) * S_ + ss] = val;
      }
  }
}

// Out-proj: C = A[M,K] * W[N,K]^T + bias, fp32 out. 128x64 tiles, 2-phase dbuf.
__global__ __launch_bounds__(256, 2)
void gemm_out(const u16* __restrict__ A, const u16* __restrict__ W,
              const float* __restrict__ bias, float* __restrict__ outf,
              int M, int N, int K)
{
  __shared__ __align__(16) u16 As[2][128 * 32];
  __shared__ __align__(16) u16 Bs[2][64 * 32];
  const int tid = threadIdx.x;
  const int w = tid >> 6, l = tid & 63;
  const int lg = l >> 4, lr = l & 15;
  const int tM = blockIdx.y * 128, tN = blockIdx.x * 64;

  f32x4 acc[2][4];
  const f32x4 z4 = {0.f, 0.f, 0.f, 0.f};
#pragma unroll
  for (int m = 0; m < 2; ++m)
#pragma unroll
    for (int n = 0; n < 4; ++n) acc[m][n] = z4;

  auto STG = [&](int buf, int k0) {
#pragma unroll
    for (int i = 0; i < 2; ++i) {
      const int ch = i * 256 + tid;
      const int row = ch >> 2, cc = (ch & 3) * 8;
      gload_lds16(A + (size_t)(tM + row) * K + k0 + cc, As[buf] + (size_t)(i * 256 + w * 64) * 8);
    }
    gload_lds16(W + (size_t)(tN + (tid >> 2)) * K + k0 + (tid & 3) * 8, Bs[buf] + (size_t)(w * 64) * 8);
  };

  STG(0, 0);
  __syncthreads();

  for (int it = 0; it < K / 32; ++it) {
    const int cur = it & 1;
    if (it + 1 < K / 32) STG(cur ^ 1, (it + 1) * 32);
    bf16x8 af[2], bw[4];
#pragma unroll
    for (int m = 0; m < 2; ++m)
      af[m] = *(const bf16x8*)&As[cur][(w * 32 + m * 16 + lr) * 32 + lg * 8];
#pragma unroll
    for (int n = 0; n < 4; ++n)
      bw[n] = *(const bf16x8*)&Bs[cur][(n * 16 + lr) * 32 + lg * 8];
#pragma unroll
    for (int m = 0; m < 2; ++m)
#pragma unroll
      for (int n = 0; n < 4; ++n)
        acc[m][n] = __builtin_amdgcn_mfma_f32_16x16x32_bf16(af[m], bw[n], acc[m][n], 0, 0, 0);
    __syncthreads();
  }

#pragma unroll
  for (int n = 0; n < 4; ++n) {
    const int col = tN + n * 16 + lr;
    const float bv = bias[col];
#pragma unroll
    for (int m = 0; m < 2; ++m)
#pragma unroll
      for (int r = 0; r < 4; ++r) {
        const int row = tM + w * 32 + m * 16 + lg * 4 + r;
        outf[(size_t)row * N + col] = acc[m][n][r] + bv;
      }
  }
}

// Flash attention, BARRIER-FREE: each wave owns a private double-buffered
// K[32x64]/V[64x32] LDS ring (16KB/wave, 64KB/block -> 2 blocks/CU) staged
// with its own global_load_lds and guarded by own-wave counted
// s_waitcnt vmcnt(8) -- no __syncthreads anywhere in the loop, so the 8
// waves/CU de-phase and interleave LDS/VALU/MFMA bursts instead of
// convoying. Math/layout identical to the verified R6 kernel (32x32x16
// MFMA, in-register P via cvt_pk+permlane32_swap, zero-shift softmax,
// same XOR swizzle geometry); KVB=32 is R6's per-kt half. Grid 512,
// bh in low 5 bits for XCD-local K/V (L2-resident; 4x wave-level reuse
// is absorbed by L2).
__global__ __launch_bounds__(256, 2)
void attn_fwd(const u16* __restrict__ qb, const u16* __restrict__ kb,
              const u16* __restrict__ vtb, u16* __restrict__ ob)
{
  __shared__ __align__(16) u16 smem[32768];   // 64 KB = 4 waves x 16 KB

  const int tid = threadIdx.x;
  const int w = tid >> 6, l = tid & 63;
  const int q32 = l & 31, hi = l >> 5;
  const int idx = blockIdx.x;
  const int bh = idx & 31, qt = idx >> 5;
  const int bb = bh >> 4, hh = bh & 15;
  const int q0 = qt * 128 + w * 32;

  u16* Kb = smem + w * 8192;          // K: 2 bufs x 2048 u16 ([32 kv][64 d])
  u16* Vb = smem + w * 8192 + 4096;   // V: 2 bufs x 2048 u16 ([64 d][32 kv])

  // Q (B-operand): lane holds Q[q0+q32][ks*16 + hi*8 + j]
  bf16x8 qf[4];
#pragma unroll
  for (int ks = 0; ks < 4; ++ks)
    qf[ks] = *(const bf16x8*)&qb[((size_t)bh * S_ + q0 + q32) * HD_ + ks * 16 + hi * 8];

  const f32x16 z16 = {};
  f32x16 acc[2] = {z16, z16};   // O^T: d = (r&3)+8(r>>2)+4hi+32dt, q = q32
  float lrun = 0.f;

  // per-lane pre-swizzled global sources (linear LDS dest -> swizzled layout):
  // K LDS[r][s8] = src col s8^(r&7); V LDS[r][s4] = src col s4^(r&3)
  const u16* ksrcl = kb  + ((size_t)bh * S_  + (l >> 3)) * HD_ + (((l & 7) ^ (l >> 3)) << 3);
  const u16* vsrcl = vtb + ((size_t)bh * HD_ + (l >> 2)) * S_  + (((l & 3) ^ ((l >> 2) & 3)) << 3);

  auto STAGE = [&](int buf, int t) {
#pragma unroll
    for (int j = 0; j < 4; ++j)   // K: 8 rows per load
      gload_lds16(ksrcl + ((size_t)t * 32 + j * 8) * HD_, Kb + buf * 2048 + j * 512);
#pragma unroll
    for (int j = 0; j < 4; ++j)   // V: 16 d-rows per load
      gload_lds16(vsrcl + (size_t)t * 32 + (size_t)j * 16 * S_, Vb + buf * 2048 + j * 512);
  };

  STAGE(0, 0);

  const int swK = q32 & 7;
  const int swV = q32 & 3;

  for (int t = 0; t < 64; ++t) {
    const int cur = t & 1;
    if (t + 1 < 64) {
      STAGE(cur ^ 1, t + 1);
      asm volatile("s_waitcnt vmcnt(8)" ::: "memory");  // tile t landed; t+1 in flight
    } else {
      asm volatile("s_waitcnt vmcnt(0)" ::: "memory");
    }
    const u16* Kt = Kb + cur * 2048;
    const u16* Vt = Vb + cur * 2048;

    // QK^T: st = S^T[kv 32][q 32]
    f32x16 st = z16;
    __builtin_amdgcn_s_setprio(1);
#pragma unroll
    for (int ks = 0; ks < 4; ++ks) {
      const bf16x8 kf = *(const bf16x8*)&Kt[q32 * 64 + (((ks * 2 + hi) ^ swK) << 3)];
      st = __builtin_amdgcn_mfma_f32_32x32x16_bf16(kf, qf[ks], st, 0, 0, 0);
    }
    __builtin_amdgcn_s_setprio(0);

    // softmax (p = 2^s) + pack + permlane32_swap -> PV B-operand frags
    float p[16];
#pragma unroll
    for (int r = 0; r < 16; ++r) p[r] = ex2(st[r]);
#pragma unroll
    for (int g = 0; g < 4; ++g)
      lrun += (p[4 * g] + p[4 * g + 1]) + (p[4 * g + 2] + p[4 * g + 3]);
    u32 wk0[4], wk1[4];
#pragma unroll
    for (int g = 0; g < 4; ++g) {
      wk0[g] = cvtpk(p[4 * g], p[4 * g + 1]);
      wk1[g] = cvtpk(p[4 * g + 2], p[4 * g + 3]);
    }
    bf16x8 pa[2];
#pragma unroll
    for (int k2 = 0; k2 < 2; ++k2) {
      u32 a0 = wk0[2 * k2], b0 = wk0[2 * k2 + 1];
      u32 a1 = wk1[2 * k2], b1 = wk1[2 * k2 + 1];
      asm volatile("v_permlane32_swap_b32 %0, %1" : "+v"(a0), "+v"(b0));
      asm volatile("v_permlane32_swap_b32 %0, %1" : "+v"(a1), "+v"(b1));
      uint4 wv = {a0, a1, b0, b1};
      pa[k2] = __builtin_bit_cast(bf16x8, wv);
    }

    // PV: acc[dt] += V^T-frag x pa -> O^T[d][q]
    __builtin_amdgcn_s_setprio(1);
#pragma unroll
    for (int dt = 0; dt < 2; ++dt)
#pragma unroll
      for (int k2 = 0; k2 < 2; ++k2) {
        const bf16x8 vf = *(const bf16x8*)&Vt[(dt * 32 + q32) * 32 + (((k2 * 2 + hi) ^ swV) << 3)];
        acc[dt] = __builtin_amdgcn_mfma_f32_32x32x16_bf16(vf, pa[k2], acc[dt], 0, 0, 0);
      }
    __builtin_amdgcn_s_setprio(0);
  }

  // lane holds half the kv-range (hi split); partner lane l^32 has the rest
  lrun += __shfl_xor(lrun, 32);
  const float linv = 1.f / lrun;
  const size_t orow = ((size_t)(bb * S_ + q0 + q32)) * H_ + hh * HD_;
#pragma unroll
  for (int dt = 0; dt < 2; ++dt)
#pragma unroll
    for (int g = 0; g < 4; ++g) {
      const u32 o0 = cvtpk(acc[dt][4 * g] * linv, acc[dt][4 * g + 1] * linv);
      const u32 o1 = cvtpk(acc[dt][4 * g + 2] * linv, acc[dt][4 * g + 3] * linv);
      uint2 ov; ov.x = o0; ov.y = o1;
      *(uint2*)&ob[orow + dt * 32 + g * 8 + hi * 4] = ov;
    }
}

extern "C" void kernel_launch(void* const* d_in, const int* in_sizes, int n_in,
                              void* d_out, int out_size, void* d_ws, size_t ws_size,
                              hipStream_t stream) {
  const float* x     = (const float*)d_in[0];
  const float* qkv_w = (const float*)d_in[1];
  const float* qkv_b = (const float*)d_in[2];
  const float* out_w = (const float*)d_in[3];
  const float* out_b = (const float*)d_in[4];

  char* ws = (char*)d_ws;
  u16* xb    = (u16*)(ws);
  u16* wqkvb = (u16*)(ws + 8388608);
  u16* wob   = (u16*)(ws + 14680064);
  u16* qb    = (u16*)(ws + 16777216);
  u16* kb    = (u16*)(ws + 25165824);
  u16* vtb   = (u16*)(ws + 33554432);   // V transposed: [b,h,d,s]
  u16* ob    = (u16*)(ws + 41943040);

  cvt_all<<<8192, 256, 0, stream>>>(x, qkv_w, out_w, xb, wqkvb, wob);

  gemm_qkv<<<dim3(24, 32), 256, 0, stream>>>(xb, wqkvb, qkv_b,
                                             qb, kb, vtb, 4096, 3072, 1024);
  attn_fwd<<<512, 256, 0, stream>>>(qb, kb, vtb, ob);
  gemm_out<<<dim3(16, 32), 256, 0, stream>>>(ob, wob, out_b, (float*)d_out,
                                             4096, 1024, 1024);
}

// Round 10
// 117.919 us; speedup vs baseline: 1.6081x; 1.0383x over previous
//
#include <hip/hip_runtime.h>
#include <stdint.h>

typedef __bf16 bf16x8 __attribute__((ext_vector_type(8)));
typedef float  f32x4  __attribute__((ext_vector_type(4)));
typedef float  f32x16 __attribute__((ext_vector_type(16)));
typedef unsigned short u16;
typedef unsigned int   u32;

#define B_  2
#define S_  2048
#define H_  1024
#define NH_ 16
#define HD_ 64
#define QSCL 0.18033688011112042f  /* 0.125 * log2(e) */

__device__ __forceinline__ u16 f2bf(float f) {
  u32 u = __builtin_bit_cast(u32, f);
  return (u16)((u + 0x7FFFu + ((u >> 16) & 1u)) >> 16);
}
__device__ __forceinline__ float ex2(float x) { return __builtin_amdgcn_exp2f(x); }
__device__ __forceinline__ u32 cvtpk(float lo, float hi) {
  u32 r; asm("v_cvt_pk_bf16_f32 %0, %1, %2" : "=v"(r) : "v"(lo), "v"(hi)); return r;
}
__device__ __forceinline__ void gload_lds16(const u16* g, u16* lds) {
  __builtin_amdgcn_global_load_lds(
      (__attribute__((address_space(1))) void*)(void*)g,
      (__attribute__((address_space(3))) void*)lds, 16, 0, 0);
}

__global__ void cvt_all(const float* __restrict__ a, const float* __restrict__ b,
                        const float* __restrict__ c, u16* __restrict__ oa,
                        u16* __restrict__ ob, u16* __restrict__ oc) {
  int i = blockIdx.x * 256 + threadIdx.x;
  const float4* src; ushort4* dst; int j;
  if (i < 1048576)      { src = (const float4*)a; dst = (ushort4*)oa; j = i; }
  else if (i < 1835008) { src = (const float4*)b; dst = (ushort4*)ob; j = i - 1048576; }
  else                  { src = (const float4*)c; dst = (ushort4*)oc; j = i - 1835008; }
  const float4 v = src[j];
  ushort4 o;
  o.x = f2bf(v.x); o.y = f2bf(v.y); o.z = f2bf(v.z); o.w = f2bf(v.w);
  dst[j] = o;
}

// QKV GEMM: C = A[M,K] * W[N,K]^T + bias, scatter bf16 to q (pre-scaled)/k/v,
// ALL in [b,h,s,d] (coalesced 32B-chunk stores; no transposed scatter).
__global__ __launch_bounds__(256, 2)
void gemm_qkv(const u16* __restrict__ A, const u16* __restrict__ W,
              const float* __restrict__ bias,
              u16* __restrict__ qb, u16* __restrict__ kb, u16* __restrict__ vb,
              int M, int N, int K)
{
  __shared__ __align__(16) u16 As[2][128 * 32];
  __shared__ __align__(16) u16 Bs[2][128 * 32];
  const int tid = threadIdx.x;
  const int w = tid >> 6, l = tid & 63;
  const int lg = l >> 4, lr = l & 15;
  const int wr = w >> 1, wc = w & 1;
  const int tM = blockIdx.y * 128, tN = blockIdx.x * 128;

  f32x4 acc[4][4];
  const f32x4 z4 = {0.f, 0.f, 0.f, 0.f};
#pragma unroll
  for (int m = 0; m < 4; ++m)
#pragma unroll
    for (int n = 0; n < 4; ++n) acc[m][n] = z4;

  auto STG = [&](int buf, int k0) {
#pragma unroll
    for (int i = 0; i < 2; ++i) {
      const int ch = i * 256 + tid;
      const int row = ch >> 2, cc = (ch & 3) * 8;
      gload_lds16(A + (size_t)(tM + row) * K + k0 + cc, As[buf] + (size_t)(i * 256 + w * 64) * 8);
      gload_lds16(W + (size_t)(tN + row) * K + k0 + cc, Bs[buf] + (size_t)(i * 256 + w * 64) * 8);
    }
  };

  STG(0, 0);
  __syncthreads();

  for (int it = 0; it < K / 32; ++it) {
    const int cur = it & 1;
    if (it + 1 < K / 32) STG(cur ^ 1, (it + 1) * 32);
    bf16x8 af[4], bw[4];
#pragma unroll
    for (int m = 0; m < 4; ++m)
      af[m] = *(const bf16x8*)&As[cur][(wr * 64 + m * 16 + lr) * 32 + lg * 8];
#pragma unroll
    for (int n = 0; n < 4; ++n)
      bw[n] = *(const bf16x8*)&Bs[cur][(wc * 64 + n * 16 + lr) * 32 + lg * 8];
#pragma unroll
    for (int m = 0; m < 4; ++m)
#pragma unroll
      for (int n = 0; n < 4; ++n)
        acc[m][n] = __builtin_amdgcn_mfma_f32_16x16x32_bf16(af[m], bw[n], acc[m][n], 0, 0, 0);
    __syncthreads();
  }

#pragma unroll
  for (int n = 0; n < 4; ++n) {
    const int col = tN + wc * 64 + n * 16 + lr;
    const float bv = bias[col];
    const int t3 = col >> 10, rem = col & 1023;
    const int hh = rem >> 6, dd = rem & 63;
    const float sc = (t3 == 0) ? QSCL : 1.f;
    u16* dst = (t3 == 0) ? qb : (t3 == 1) ? kb : vb;
#pragma unroll
    for (int m = 0; m < 4; ++m)
#pragma unroll
      for (int r = 0; r < 4; ++r) {
        const int row = tM + wr * 64 + m * 16 + lg * 4 + r;
        const int bb = row >> 11, ss = row & 2047;
        dst[((size_t)(bb * NH_ + hh) * S_ + ss) * HD_ + dd] = f2bf((acc[m][n][r] + bv) * sc);
      }
  }
}

// Transpose v [b,h,s,d] -> vt [b,h,d,s]. 64x64 LDS tiles, pad 65 (<=2-way
// conflicts), coalesced 128B on both global sides. Grid (32 s-chunks, 32 bh).
__global__ __launch_bounds__(256, 4)
void vtrans(const u16* __restrict__ vb, u16* __restrict__ vtb)
{
  __shared__ u16 Ls[64 * 65];
  const int t = threadIdx.x;
  const int bh = blockIdx.y;
  const int s0 = blockIdx.x * 64;
  const u16* src = vb + ((size_t)bh * S_ + s0) * HD_;
  const int d = t & 63, sy = t >> 6;
#pragma unroll
  for (int p = 0; p < 16; ++p) {
    const int s = p * 4 + sy;
    Ls[s * 65 + d] = src[(size_t)s * HD_ + d];
  }
  __syncthreads();
  const int s = t & 63, dy = t >> 6;
  u16* dst = vtb + (size_t)bh * HD_ * S_ + s0;
#pragma unroll
  for (int p = 0; p < 16; ++p) {
    const int dd = p * 4 + dy;
    dst[(size_t)dd * S_ + s] = Ls[s * 65 + dd];
  }
}

// Out-proj: C = A[M,K] * W[N,K]^T + bias, fp32 out. 128x64 tiles, 2-phase dbuf.
__global__ __launch_bounds__(256, 2)
void gemm_out(const u16* __restrict__ A, const u16* __restrict__ W,
              const float* __restrict__ bias, float* __restrict__ outf,
              int M, int N, int K)
{
  __shared__ __align__(16) u16 As[2][128 * 32];
  __shared__ __align__(16) u16 Bs[2][64 * 32];
  const int tid = threadIdx.x;
  const int w = tid >> 6, l = tid & 63;
  const int lg = l >> 4, lr = l & 15;
  const int tM = blockIdx.y * 128, tN = blockIdx.x * 64;

  f32x4 acc[2][4];
  const f32x4 z4 = {0.f, 0.f, 0.f, 0.f};
#pragma unroll
  for (int m = 0; m < 2; ++m)
#pragma unroll
    for (int n = 0; n < 4; ++n) acc[m][n] = z4;

  auto STG = [&](int buf, int k0) {
#pragma unroll
    for (int i = 0; i < 2; ++i) {
      const int ch = i * 256 + tid;
      const int row = ch >> 2, cc = (ch & 3) * 8;
      gload_lds16(A + (size_t)(tM + row) * K + k0 + cc, As[buf] + (size_t)(i * 256 + w * 64) * 8);
    }
    gload_lds16(W + (size_t)(tN + (tid >> 2)) * K + k0 + (tid & 3) * 8, Bs[buf] + (size_t)(w * 64) * 8);
  };

  STG(0, 0);
  __syncthreads();

  for (int it = 0; it < K / 32; ++it) {
    const int cur = it & 1;
    if (it + 1 < K / 32) STG(cur ^ 1, (it + 1) * 32);
    bf16x8 af[2], bw[4];
#pragma unroll
    for (int m = 0; m < 2; ++m)
      af[m] = *(const bf16x8*)&As[cur][(w * 32 + m * 16 + lr) * 32 + lg * 8];
#pragma unroll
    for (int n = 0; n < 4; ++n)
      bw[n] = *(const bf16x8*)&Bs[cur][(n * 16 + lr) * 32 + lg * 8];
#pragma unroll
    for (int m = 0; m < 2; ++m)
#pragma unroll
      for (int n = 0; n < 4; ++n)
        acc[m][n] = __builtin_amdgcn_mfma_f32_16x16x32_bf16(af[m], bw[n], acc[m][n], 0, 0, 0);
    __syncthreads();
  }

#pragma unroll
  for (int n = 0; n < 4; ++n) {
    const int col = tN + n * 16 + lr;
    const float bv = bias[col];
#pragma unroll
    for (int m = 0; m < 2; ++m)
#pragma unroll
      for (int r = 0; r < 4; ++r) {
        const int row = tM + w * 32 + m * 16 + lg * 4 + r;
        outf[(size_t)row * N + col] = acc[m][n][r] + bv;
      }
  }
}

// Flash attention (exact R6 structure, proven 52.6us): 32x32x16 MFMA,
// in-register P (cvt_pk + permlane32_swap), zero-shift softmax. QBLK=128
// (4 waves x 32 q), KVBLK=64 double-buffered via pre-swizzled
// global_load_lds. LDS 32KB. Grid 512, bh in low 5 bits (XCD-local K/V).
__global__ __launch_bounds__(256, 2)
void attn_fwd(const u16* __restrict__ qb, const u16* __restrict__ kb,
              const u16* __restrict__ vtb, u16* __restrict__ ob)
{
  __shared__ __align__(16) u16 Kl[2][64 * 64];
  __shared__ __align__(16) u16 Vl[2][64 * 64];

  const int tid = threadIdx.x;
  const int w = tid >> 6, l = tid & 63;
  const int q32 = l & 31, hi = l >> 5;
  const int idx = blockIdx.x;
  const int bh = idx & 31, qt = idx >> 5;
  const int bb = bh >> 4, hh = bh & 15;
  const int q0 = qt * 128 + w * 32;

  bf16x8 qf[4];
#pragma unroll
  for (int ks = 0; ks < 4; ++ks)
    qf[ks] = *(const bf16x8*)&qb[((size_t)bh * S_ + q0 + q32) * HD_ + ks * 16 + hi * 8];

  const f32x16 z16 = {};
  f32x16 acc[2] = {z16, z16};
  float lrun = 0.f;

  const int srow = l >> 3;
  const int scol = ((l & 7) ^ srow) << 3;
  const u16* kbase = kb  + ((size_t)bh * S_  + w * 16 + srow) * HD_ + scol;
  const u16* vbase = vtb + ((size_t)bh * HD_ + w * 16 + srow) * S_  + scol;

  auto STAGE = [&](int buf, int t) {
#pragma unroll
    for (int j = 0; j < 2; ++j) {
      gload_lds16(kbase + (size_t)t * 64 * HD_ + j * 8 * HD_, &Kl[buf][(w * 16 + j * 8) * 64]);
      gload_lds16(vbase + (size_t)t * 64 + j * 8 * S_,        &Vl[buf][(w * 16 + j * 8) * 64]);
    }
  };

  STAGE(0, 0);
  __syncthreads();

  const int sw = q32 & 7;

  for (int t = 0; t < 32; ++t) {
    const int cur = t & 1;
    if (t + 1 < 32) STAGE(cur ^ 1, t + 1);

    f32x16 st[2] = {z16, z16};
    __builtin_amdgcn_s_setprio(1);
#pragma unroll
    for (int kt = 0; kt < 2; ++kt)
#pragma unroll
      for (int ks = 0; ks < 4; ++ks) {
        const bf16x8 kf = *(const bf16x8*)&Kl[cur][(kt * 32 + q32) * 64 + ((((ks << 1) | hi) ^ sw) << 3)];
        st[kt] = __builtin_amdgcn_mfma_f32_32x32x16_bf16(kf, qf[ks], st[kt], 0, 0, 0);
      }
    __builtin_amdgcn_s_setprio(0);

    bf16x8 pa[4];
#pragma unroll
    for (int kt = 0; kt < 2; ++kt) {
      float p[16];
#pragma unroll
      for (int r = 0; r < 16; ++r) p[r] = ex2(st[kt][r]);
#pragma unroll
      for (int g = 0; g < 4; ++g)
        lrun += (p[4 * g] + p[4 * g + 1]) + (p[4 * g + 2] + p[4 * g + 3]);
      u32 wk0[4], wk1[4];
#pragma unroll
      for (int g = 0; g < 4; ++g) {
        wk0[g] = cvtpk(p[4 * g], p[4 * g + 1]);
        wk1[g] = cvtpk(p[4 * g + 2], p[4 * g + 3]);
      }
#pragma unroll
      for (int k2 = 0; k2 < 2; ++k2) {
        u32 a0 = wk0[2 * k2], b0 = wk0[2 * k2 + 1];
        u32 a1 = wk1[2 * k2], b1 = wk1[2 * k2 + 1];
        asm volatile("v_permlane32_swap_b32 %0, %1" : "+v"(a0), "+v"(b0));
        asm volatile("v_permlane32_swap_b32 %0, %1" : "+v"(a1), "+v"(b1));
        uint4 wv = {a0, a1, b0, b1};
        pa[kt * 2 + k2] = __builtin_bit_cast(bf16x8, wv);
      }
    }

    __builtin_amdgcn_s_setprio(1);
#pragma unroll
    for (int dt = 0; dt < 2; ++dt)
#pragma unroll
      for (int ks = 0; ks < 4; ++ks) {
        const bf16x8 vf = *(const bf16x8*)&Vl[cur][(dt * 32 + q32) * 64 + ((((ks << 1) | hi) ^ sw) << 3)];
        acc[dt] = __builtin_amdgcn_mfma_f32_32x32x16_bf16(vf, pa[ks], acc[dt], 0, 0, 0);
      }
    __builtin_amdgcn_s_setprio(0);

    __syncthreads();
  }

  lrun += __shfl_xor(lrun, 32);
  const float linv = 1.f / lrun;
  const size_t orow = ((size_t)(bb * S_ + q0 + q32)) * H_ + hh * HD_;
#pragma unroll
  for (int dt = 0; dt < 2; ++dt)
#pragma unroll
    for (int g = 0; g < 4; ++g) {
      const u32 o0 = cvtpk(acc[dt][4 * g] * linv, acc[dt][4 * g + 1] * linv);
      const u32 o1 = cvtpk(acc[dt][4 * g + 2] * linv, acc[dt][4 * g + 3] * linv);
      uint2 ov; ov.x = o0; ov.y = o1;
      *(uint2*)&ob[orow + dt * 32 + g * 8 + hi * 4] = ov;
    }
}

extern "C" void kernel_launch(void* const* d_in, const int* in_sizes, int n_in,
                              void* d_out, int out_size, void* d_ws, size_t ws_size,
                              hipStream_t stream) {
  const float* x     = (const float*)d_in[0];
  const float* qkv_w = (const float*)d_in[1];
  const float* qkv_b = (const float*)d_in[2];
  const float* out_w = (const float*)d_in[3];
  const float* out_b = (const float*)d_in[4];

  char* ws = (char*)d_ws;
  u16* xb    = (u16*)(ws);              // 8 MB; dead after gemm_qkv -> reused as vtb
  u16* wqkvb = (u16*)(ws + 8388608);    // 6 MB
  u16* wob   = (u16*)(ws + 14680064);   // 2 MB
  u16* qb    = (u16*)(ws + 16777216);   // 8 MB
  u16* kb    = (u16*)(ws + 25165824);   // 8 MB
  u16* vb    = (u16*)(ws + 33554432);   // 8 MB (V natural [b,h,s,d])
  u16* ob    = (u16*)(ws + 41943040);   // 8 MB -> 48 MB total
  u16* vtb   = xb;                      // V transposed [b,h,d,s], aliases xb

  cvt_all<<<8192, 256, 0, stream>>>(x, qkv_w, out_w, xb, wqkvb, wob);

  gemm_qkv<<<dim3(24, 32), 256, 0, stream>>>(xb, wqkvb, qkv_b,
                                             qb, kb, vb, 4096, 3072, 1024);
  vtrans<<<dim3(32, 32), 256, 0, stream>>>(vb, vtb);
  attn_fwd<<<512, 256, 0, stream>>>(qb, kb, vtb, ob);
  gemm_out<<<dim3(16, 32), 256, 0, stream>>>(ob, wob, out_b, (float*)d_out,
                                             4096, 1024, 1024);
}

// Round 11
// 114.903 us; speedup vs baseline: 1.6503x; 1.0262x over previous
//
#include <hip/hip_runtime.h>
#include <stdint.h>

typedef __bf16 bf16x8 __attribute__((ext_vector_type(8)));
typedef float  f32x4  __attribute__((ext_vector_type(4)));
typedef float  f32x16 __attribute__((ext_vector_type(16)));
typedef unsigned short u16;
typedef unsigned int   u32;

#define B_  2
#define S_  2048
#define H_  1024
#define NH_ 16
#define HD_ 64
#define QSCL 0.18033688011112042f  /* 0.125 * log2(e) */

__device__ __forceinline__ u16 f2bf(float f) {
  u32 u = __builtin_bit_cast(u32, f);
  return (u16)((u + 0x7FFFu + ((u >> 16) & 1u)) >> 16);
}
__device__ __forceinline__ float ex2(float x) { return __builtin_amdgcn_exp2f(x); }
__device__ __forceinline__ u32 cvtpk(float lo, float hi) {
  u32 r; asm("v_cvt_pk_bf16_f32 %0, %1, %2" : "=v"(r) : "v"(lo), "v"(hi)); return r;
}
__device__ __forceinline__ void gload_lds16(const u16* g, u16* lds) {
  __builtin_amdgcn_global_load_lds(
      (__attribute__((address_space(1))) void*)(void*)g,
      (__attribute__((address_space(3))) void*)lds, 16, 0, 0);
}

__global__ void cvt_all(const float* __restrict__ a, const float* __restrict__ b,
                        const float* __restrict__ c, u16* __restrict__ oa,
                        u16* __restrict__ ob, u16* __restrict__ oc) {
  int i = blockIdx.x * 256 + threadIdx.x;
  const float4* src; ushort4* dst; int j;
  if (i < 1048576)      { src = (const float4*)a; dst = (ushort4*)oa; j = i; }
  else if (i < 1835008) { src = (const float4*)b; dst = (ushort4*)ob; j = i - 1048576; }
  else                  { src = (const float4*)c; dst = (ushort4*)oc; j = i - 1835008; }
  const float4 v = src[j];
  ushort4 o;
  o.x = f2bf(v.x); o.y = f2bf(v.y); o.z = f2bf(v.z); o.w = f2bf(v.w);
  dst[j] = o;
}

// QKV GEMM: C = A[M,K] * W[N,K]^T + bias, scatter bf16 to q (pre-scaled)/k/v,
// ALL in [b,h,s,d] (coalesced stores). 2-phase double-buffered staging.
__global__ __launch_bounds__(256, 2)
void gemm_qkv(const u16* __restrict__ A, const u16* __restrict__ W,
              const float* __restrict__ bias,
              u16* __restrict__ qb, u16* __restrict__ kb, u16* __restrict__ vb,
              int M, int N, int K)
{
  __shared__ __align__(16) u16 As[2][128 * 32];
  __shared__ __align__(16) u16 Bs[2][128 * 32];
  const int tid = threadIdx.x;
  const int w = tid >> 6, l = tid & 63;
  const int lg = l >> 4, lr = l & 15;
  const int wr = w >> 1, wc = w & 1;
  const int tM = blockIdx.y * 128, tN = blockIdx.x * 128;

  f32x4 acc[4][4];
  const f32x4 z4 = {0.f, 0.f, 0.f, 0.f};
#pragma unroll
  for (int m = 0; m < 4; ++m)
#pragma unroll
    for (int n = 0; n < 4; ++n) acc[m][n] = z4;

  auto STG = [&](int buf, int k0) {
#pragma unroll
    for (int i = 0; i < 2; ++i) {
      const int ch = i * 256 + tid;
      const int row = ch >> 2, cc = (ch & 3) * 8;
      gload_lds16(A + (size_t)(tM + row) * K + k0 + cc, As[buf] + (size_t)(i * 256 + w * 64) * 8);
      gload_lds16(W + (size_t)(tN + row) * K + k0 + cc, Bs[buf] + (size_t)(i * 256 + w * 64) * 8);
    }
  };

  STG(0, 0);
  __syncthreads();

  for (int it = 0; it < K / 32; ++it) {
    const int cur = it & 1;
    if (it + 1 < K / 32) STG(cur ^ 1, (it + 1) * 32);
    bf16x8 af[4], bw[4];
#pragma unroll
    for (int m = 0; m < 4; ++m)
      af[m] = *(const bf16x8*)&As[cur][(wr * 64 + m * 16 + lr) * 32 + lg * 8];
#pragma unroll
    for (int n = 0; n < 4; ++n)
      bw[n] = *(const bf16x8*)&Bs[cur][(wc * 64 + n * 16 + lr) * 32 + lg * 8];
#pragma unroll
    for (int m = 0; m < 4; ++m)
#pragma unroll
      for (int n = 0; n < 4; ++n)
        acc[m][n] = __builtin_amdgcn_mfma_f32_16x16x32_bf16(af[m], bw[n], acc[m][n], 0, 0, 0);
    __syncthreads();
  }

#pragma unroll
  for (int n = 0; n < 4; ++n) {
    const int col = tN + wc * 64 + n * 16 + lr;
    const float bv = bias[col];
    const int t3 = col >> 10, rem = col & 1023;
    const int hh = rem >> 6, dd = rem & 63;
    const float sc = (t3 == 0) ? QSCL : 1.f;
    u16* dst = (t3 == 0) ? qb : (t3 == 1) ? kb : vb;
#pragma unroll
    for (int m = 0; m < 4; ++m)
#pragma unroll
      for (int r = 0; r < 4; ++r) {
        const int row = tM + wr * 64 + m * 16 + lg * 4 + r;
        const int bb = row >> 11, ss = row & 2047;
        dst[((size_t)(bb * NH_ + hh) * S_ + ss) * HD_ + dd] = f2bf((acc[m][n][r] + bv) * sc);
      }
  }
}

// Transpose v [b,h,s,d] -> vt [b,h,d,s]. 64x64 LDS tiles, pad 65.
__global__ __launch_bounds__(256, 4)
void vtrans(const u16* __restrict__ vb, u16* __restrict__ vtb)
{
  __shared__ u16 Ls[64 * 65];
  const int t = threadIdx.x;
  const int bh = blockIdx.y;
  const int s0 = blockIdx.x * 64;
  const u16* src = vb + ((size_t)bh * S_ + s0) * HD_;
  const int d = t & 63, sy = t >> 6;
#pragma unroll
  for (int p = 0; p < 16; ++p) {
    const int s = p * 4 + sy;
    Ls[s * 65 + d] = src[(size_t)s * HD_ + d];
  }
  __syncthreads();
  const int s = t & 63, dy = t >> 6;
  u16* dst = vtb + (size_t)bh * HD_ * S_ + s0;
#pragma unroll
  for (int p = 0; p < 16; ++p) {
    const int dd = p * 4 + dy;
    dst[(size_t)dd * S_ + s] = Ls[s * 65 + dd];
  }
}

// Out-proj: C = A[M,K] * W[N,K]^T + bias, fp32 out. 128x64 tiles, 2-phase dbuf.
__global__ __launch_bounds__(256, 2)
void gemm_out(const u16* __restrict__ A, const u16* __restrict__ W,
              const float* __restrict__ bias, float* __restrict__ outf,
              int M, int N, int K)
{
  __shared__ __align__(16) u16 As[2][128 * 32];
  __shared__ __align__(16) u16 Bs[2][64 * 32];
  const int tid = threadIdx.x;
  const int w = tid >> 6, l = tid & 63;
  const int lg = l >> 4, lr = l & 15;
  const int tM = blockIdx.y * 128, tN = blockIdx.x * 64;

  f32x4 acc[2][4];
  const f32x4 z4 = {0.f, 0.f, 0.f, 0.f};
#pragma unroll
  for (int m = 0; m < 2; ++m)
#pragma unroll
    for (int n = 0; n < 4; ++n) acc[m][n] = z4;

  auto STG = [&](int buf, int k0) {
#pragma unroll
    for (int i = 0; i < 2; ++i) {
      const int ch = i * 256 + tid;
      const int row = ch >> 2, cc = (ch & 3) * 8;
      gload_lds16(A + (size_t)(tM + row) * K + k0 + cc, As[buf] + (size_t)(i * 256 + w * 64) * 8);
    }
    gload_lds16(W + (size_t)(tN + (tid >> 2)) * K + k0 + (tid & 3) * 8, Bs[buf] + (size_t)(w * 64) * 8);
  };

  STG(0, 0);
  __syncthreads();

  for (int it = 0; it < K / 32; ++it) {
    const int cur = it & 1;
    if (it + 1 < K / 32) STG(cur ^ 1, (it + 1) * 32);
    bf16x8 af[2], bw[4];
#pragma unroll
    for (int m = 0; m < 2; ++m)
      af[m] = *(const bf16x8*)&As[cur][(w * 32 + m * 16 + lr) * 32 + lg * 8];
#pragma unroll
    for (int n = 0; n < 4; ++n)
      bw[n] = *(const bf16x8*)&Bs[cur][(n * 16 + lr) * 32 + lg * 8];
#pragma unroll
    for (int m = 0; m < 2; ++m)
#pragma unroll
      for (int n = 0; n < 4; ++n)
        acc[m][n] = __builtin_amdgcn_mfma_f32_16x16x32_bf16(af[m], bw[n], acc[m][n], 0, 0, 0);
    __syncthreads();
  }

#pragma unroll
  for (int n = 0; n < 4; ++n) {
    const int col = tN + n * 16 + lr;
    const float bv = bias[col];
#pragma unroll
    for (int m = 0; m < 2; ++m)
#pragma unroll
      for (int r = 0; r < 4; ++r) {
        const int row = tM + w * 32 + m * 16 + lg * 4 + r;
        outf[(size_t)row * N + col] = acc[m][n][r] + bv;
      }
  }
}

// Flash attention: R10 structure with KVBLK=128 per barrier (two independent
// 64-kv sub-tiles A/B between barriers). Per-subtile LDS geometry/swizzle is
// EXACTLY the verified R10 layout ([64][64] u16, 128B rows, slot^=(row&7)).
// Barriers 32->16; QK^T-A and QK^T-B are independent MFMA chains (2x chain
// ILP); 8 waves/CU de-phase over the longer barrier-free stretch.
// 32x32x16 MFMA, in-register P via cvt_pk+permlane32_swap, zero-shift softmax.
// LDS 64KB -> 2 blocks/CU. Grid 512, bh in low 5 bits (XCD-local K/V).
__global__ __launch_bounds__(256, 2)
void attn_fwd(const u16* __restrict__ qb, const u16* __restrict__ kb,
              const u16* __restrict__ vtb, u16* __restrict__ ob)
{
  __shared__ __align__(16) u16 Kl[2][2][64 * 64];
  __shared__ __align__(16) u16 Vl[2][2][64 * 64];

  const int tid = threadIdx.x;
  const int w = tid >> 6, l = tid & 63;
  const int q32 = l & 31, hi = l >> 5;
  const int idx = blockIdx.x;
  const int bh = idx & 31, qt = idx >> 5;
  const int bb = bh >> 4, hh = bh & 15;
  const int q0 = qt * 128 + w * 32;

  bf16x8 qf[4];
#pragma unroll
  for (int ks = 0; ks < 4; ++ks)
    qf[ks] = *(const bf16x8*)&qb[((size_t)bh * S_ + q0 + q32) * HD_ + ks * 16 + hi * 8];

  const f32x16 z16 = {};
  f32x16 acc[2] = {z16, z16};
  float lrun = 0.f;

  const int srow = l >> 3;
  const int scol = ((l & 7) ^ srow) << 3;
  const u16* kbase = kb  + ((size_t)bh * S_  + w * 16 + srow) * HD_ + scol;
  const u16* vbase = vtb + ((size_t)bh * HD_ + w * 16 + srow) * S_  + scol;

  auto STAGE = [&](int buf, int t) {
#pragma unroll
    for (int s = 0; s < 2; ++s)
#pragma unroll
      for (int j = 0; j < 2; ++j) {
        gload_lds16(kbase + ((size_t)t * 128 + s * 64) * HD_ + j * 8 * HD_,
                    &Kl[buf][s][(w * 16 + j * 8) * 64]);
        gload_lds16(vbase + (size_t)t * 128 + s * 64 + j * 8 * S_,
                    &Vl[buf][s][(w * 16 + j * 8) * 64]);
      }
  };

  STAGE(0, 0);
  __syncthreads();

  const int sw = q32 & 7;

  // softmax + pack for one 64-kv sub-tile held in st0/st1 -> pa[4]
  auto SOFTMAX = [&](f32x16& st0, f32x16& st1, bf16x8* pa) {
#pragma unroll
    for (int kt = 0; kt < 2; ++kt) {
      const f32x16& stt = kt ? st1 : st0;
      float p[16];
#pragma unroll
      for (int r = 0; r < 16; ++r) p[r] = ex2(stt[r]);
#pragma unroll
      for (int g = 0; g < 4; ++g)
        lrun += (p[4 * g] + p[4 * g + 1]) + (p[4 * g + 2] + p[4 * g + 3]);
      u32 wk0[4], wk1[4];
#pragma unroll
      for (int g = 0; g < 4; ++g) {
        wk0[g] = cvtpk(p[4 * g], p[4 * g + 1]);
        wk1[g] = cvtpk(p[4 * g + 2], p[4 * g + 3]);
      }
#pragma unroll
      for (int k2 = 0; k2 < 2; ++k2) {
        u32 a0 = wk0[2 * k2], b0 = wk0[2 * k2 + 1];
        u32 a1 = wk1[2 * k2], b1 = wk1[2 * k2 + 1];
        asm volatile("v_permlane32_swap_b32 %0, %1" : "+v"(a0), "+v"(b0));
        asm volatile("v_permlane32_swap_b32 %0, %1" : "+v"(a1), "+v"(b1));
        uint4 wv = {a0, a1, b0, b1};
        pa[kt * 2 + k2] = __builtin_bit_cast(bf16x8, wv);
      }
    }
  };

  for (int t = 0; t < 16; ++t) {
    const int cur = t & 1;
    if (t + 1 < 16) STAGE(cur ^ 1, t + 1);

    // QK^T sub-tile A (kv 0..63) and B (kv 64..127): 4 independent chains
    f32x16 stA0 = z16, stA1 = z16, stB0 = z16, stB1 = z16;
    __builtin_amdgcn_s_setprio(1);
#pragma unroll
    for (int ks = 0; ks < 4; ++ks) {
      const int so = ((((ks << 1) | hi) ^ sw) << 3);
      const bf16x8 kfA0 = *(const bf16x8*)&Kl[cur][0][(q32) * 64 + so];
      const bf16x8 kfA1 = *(const bf16x8*)&Kl[cur][0][(32 + q32) * 64 + so];
      const bf16x8 kfB0 = *(const bf16x8*)&Kl[cur][1][(q32) * 64 + so];
      const bf16x8 kfB1 = *(const bf16x8*)&Kl[cur][1][(32 + q32) * 64 + so];
      stA0 = __builtin_amdgcn_mfma_f32_32x32x16_bf16(kfA0, qf[ks], stA0, 0, 0, 0);
      stA1 = __builtin_amdgcn_mfma_f32_32x32x16_bf16(kfA1, qf[ks], stA1, 0, 0, 0);
      stB0 = __builtin_amdgcn_mfma_f32_32x32x16_bf16(kfB0, qf[ks], stB0, 0, 0, 0);
      stB1 = __builtin_amdgcn_mfma_f32_32x32x16_bf16(kfB1, qf[ks], stB1, 0, 0, 0);
    }
    __builtin_amdgcn_s_setprio(0);

    // sub-tile A: softmax -> PV
    bf16x8 pa[4];
    SOFTMAX(stA0, stA1, pa);
    __builtin_amdgcn_s_setprio(1);
#pragma unroll
    for (int dt = 0; dt < 2; ++dt)
#pragma unroll
      for (int ks = 0; ks < 4; ++ks) {
        const bf16x8 vf = *(const bf16x8*)&Vl[cur][0][(dt * 32 + q32) * 64 + ((((ks << 1) | hi) ^ sw) << 3)];
        acc[dt] = __builtin_amdgcn_mfma_f32_32x32x16_bf16(vf, pa[ks], acc[dt], 0, 0, 0);
      }
    __builtin_amdgcn_s_setprio(0);

    // sub-tile B: softmax -> PV
    SOFTMAX(stB0, stB1, pa);
    __builtin_amdgcn_s_setprio(1);
#pragma unroll
    for (int dt = 0; dt < 2; ++dt)
#pragma unroll
      for (int ks = 0; ks < 4; ++ks) {
        const bf16x8 vf = *(const bf16x8*)&Vl[cur][1][(dt * 32 + q32) * 64 + ((((ks << 1) | hi) ^ sw) << 3)];
        acc[dt] = __builtin_amdgcn_mfma_f32_32x32x16_bf16(vf, pa[ks], acc[dt], 0, 0, 0);
      }
    __builtin_amdgcn_s_setprio(0);

    __syncthreads();
  }

  lrun += __shfl_xor(lrun, 32);
  const float linv = 1.f / lrun;
  const size_t orow = ((size_t)(bb * S_ + q0 + q32)) * H_ + hh * HD_;
#pragma unroll
  for (int dt = 0; dt < 2; ++dt)
#pragma unroll
    for (int g = 0; g < 4; ++g) {
      const u32 o0 = cvtpk(acc[dt][4 * g] * linv, acc[dt][4 * g + 1] * linv);
      const u32 o1 = cvtpk(acc[dt][4 * g + 2] * linv, acc[dt][4 * g + 3] * linv);
      uint2 ov; ov.x = o0; ov.y = o1;
      *(uint2*)&ob[orow + dt * 32 + g * 8 + hi * 4] = ov;
    }
}

extern "C" void kernel_launch(void* const* d_in, const int* in_sizes, int n_in,
                              void* d_out, int out_size, void* d_ws, size_t ws_size,
                              hipStream_t stream) {
  const float* x     = (const float*)d_in[0];
  const float* qkv_w = (const float*)d_in[1];
  const float* qkv_b = (const float*)d_in[2];
  const float* out_w = (const float*)d_in[3];
  const float* out_b = (const float*)d_in[4];

  char* ws = (char*)d_ws;
  u16* xb    = (u16*)(ws);              // 8 MB; dead after gemm_qkv -> reused as vtb
  u16* wqkvb = (u16*)(ws + 8388608);    // 6 MB
  u16* wob   = (u16*)(ws + 14680064);   // 2 MB
  u16* qb    = (u16*)(ws + 16777216);   // 8 MB
  u16* kb    = (u16*)(ws + 25165824);   // 8 MB
  u16* vb    = (u16*)(ws + 33554432);   // 8 MB (V natural [b,h,s,d])
  u16* ob    = (u16*)(ws + 41943040);   // 8 MB -> 48 MB total
  u16* vtb   = xb;                      // V transposed [b,h,d,s], aliases xb

  cvt_all<<<8192, 256, 0, stream>>>(x, qkv_w, out_w, xb, wqkvb, wob);

  gemm_qkv<<<dim3(24, 32), 256, 0, stream>>>(xb, wqkvb, qkv_b,
                                             qb, kb, vb, 4096, 3072, 1024);
  vtrans<<<dim3(32, 32), 256, 0, stream>>>(vb, vtb);
  attn_fwd<<<512, 256, 0, stream>>>(qb, kb, vtb, ob);
  gemm_out<<<dim3(16, 32), 256, 0, stream>>>(ob, wob, out_b, (float*)d_out,
                                             4096, 1024, 1024);
}